// Round 1
// baseline (639.128 us; speedup 1.0000x reference)
//
#include <hip/hip_runtime.h>
#include <math.h>

#define GRID_ 28
#define NPATCH 784
#define HID 256
#define NB 64
#define MROWS (NB * NPATCH)   // 50176

// ---------------- positional-encoding table: pe[784][256] ----------------
__global__ void pe_kernel(float* __restrict__ pe) {
    int idx = blockIdx.x * 256 + threadIdx.x;       // 784*256 threads
    int n = idx >> 8;
    int d = idx & 255;
    int k = d >> 1;
    // div = exp(2k * -ln(10000)/256) = exp(k * -ln(10000)/128)
    float div = expf((float)k * (-9.210340371976184f / 128.0f));
    float ang = (float)n * div;
    pe[idx] = (d & 1) ? cosf(ang) : sinf(ang);
}

// ---------------- GEMM: C[M,256] = A[M,K] @ B[K,256] (+bias [+pe]) -------
// BM=128, BN=128, BK=16; 256 threads; 8x8 per thread.
// EMBED: A is x[64,3,224,224], gathered on the fly (patchify), epilogue adds
//        b_embed + pe[n].  Otherwise A is row-major [M,K]; bias optional.
template <bool EMBED>
__global__ __launch_bounds__(256) void gemm128(
    const float* __restrict__ A, const float* __restrict__ Bw,
    const float* __restrict__ bias, const float* __restrict__ pe,
    float* __restrict__ C, int K) {
    constexpr int BM = 128, BN = 128, BK = 16;
    __shared__ float As[BK][BM];
    __shared__ float Bs[BK][BN];

    const int tid = threadIdx.x;
    const int m0 = blockIdx.x * BM;
    const int n0 = blockIdx.y * BN;
    const int tx = tid & 15;        // 16 col-groups
    const int ty = tid >> 4;        // 16 row-groups

    float acc[8][8];
#pragma unroll
    for (int i = 0; i < 8; ++i)
#pragma unroll
        for (int j = 0; j < 8; ++j) acc[i][j] = 0.0f;

    const int ar = tid >> 2;             // 0..63
    const int akc = (tid & 3) * 4;       // 0,4,8,12
    const int bk = tid >> 5;             // 0..7
    const int bn = (tid & 31) * 4;       // 0..124

    for (int k0 = 0; k0 < K; k0 += BK) {
        // ---- stage A tile (transposed into As[k][m]) ----
#pragma unroll
        for (int it = 0; it < 2; ++it) {
            int row = ar + it * 64;
            float4 v;
            if constexpr (EMBED) {
                int gr = m0 + row;               // global row = b*784+n
                int b = gr / NPATCH;
                int n = gr % NPATCH;
                int gi = n / GRID_, gj = n % GRID_;
                int k = k0 + akc;                // multiple of 4
                int c = k >> 6;
                int rem = k & 63;
                int pi = rem >> 3, pj = rem & 7; // pj in {0,4}
                const float* src =
                    A + ((size_t)(b * 3 + c) * 224 + gi * 8 + pi) * 224 +
                    gj * 8 + pj;
                v = *(const float4*)src;
            } else {
                v = *(const float4*)(A + (size_t)(m0 + row) * K + k0 + akc);
            }
            As[akc + 0][row] = v.x;
            As[akc + 1][row] = v.y;
            As[akc + 2][row] = v.z;
            As[akc + 3][row] = v.w;
        }
        // ---- stage B tile ----
#pragma unroll
        for (int it = 0; it < 2; ++it) {
            float4 v = *(const float4*)(Bw + (size_t)(k0 + bk + it * 8) * HID +
                                        n0 + bn);
            *(float4*)&Bs[bk + it * 8][bn] = v;
        }
        __syncthreads();

        // ---- inner product ----
#pragma unroll
        for (int kk = 0; kk < BK; ++kk) {
            float a[8], b[8];
            *(float4*)&a[0] = *(const float4*)&As[kk][ty * 8];
            *(float4*)&a[4] = *(const float4*)&As[kk][ty * 8 + 4];
            *(float4*)&b[0] = *(const float4*)&Bs[kk][tx * 8];
            *(float4*)&b[4] = *(const float4*)&Bs[kk][tx * 8 + 4];
#pragma unroll
            for (int i = 0; i < 8; ++i)
#pragma unroll
                for (int j = 0; j < 8; ++j) acc[i][j] += a[i] * b[j];
        }
        __syncthreads();
    }

    // ---- epilogue ----
    const int col0 = n0 + tx * 8;
#pragma unroll
    for (int i = 0; i < 8; ++i) {
        int gr = m0 + ty * 8 + i;
        float o[8];
#pragma unroll
        for (int j = 0; j < 8; ++j) o[j] = acc[i][j];
        if constexpr (EMBED) {
            int n = gr % NPATCH;
            const float* perow = pe + (size_t)n * HID + col0;
#pragma unroll
            for (int j = 0; j < 8; ++j) o[j] += bias[col0 + j] + perow[j];
        } else {
            if (bias != nullptr) {
#pragma unroll
                for (int j = 0; j < 8; ++j) o[j] += bias[col0 + j];
            }
        }
        float* crow = C + (size_t)gr * HID + col0;
        *(float4*)&crow[0] = make_float4(o[0], o[1], o[2], o[3]);
        *(float4*)&crow[4] = make_float4(o[4], o[5], o[6], o[7]);
    }
}

// ---------------- GCN aggregate: h = relu(D^-1/2 (A+I) D^-1/2 hw + b) ----
__device__ __forceinline__ float degOf(int i, int j) {
    return 1.0f + (float)((i > 0) + (i < GRID_ - 1) + (j > 0) + (j < GRID_ - 1));
}

__global__ __launch_bounds__(256) void aggregate_kernel(
    const float* __restrict__ hw, const float* __restrict__ bias,
    float* __restrict__ hout) {
    int idx = blockIdx.x * 256 + threadIdx.x;   // one float4 per thread
    // total float4 units: 50176 * 64
    int d4 = (idx & 63) * 4;
    int rn = idx >> 6;            // b*784 + n
    int n = rn % NPATCH;
    int i = n / GRID_, j = n % GRID_;

    float deg = degOf(i, j);
    float dn = rsqrtf(deg);
    const float* base = hw + (size_t)rn * HID + d4;

    float4 v = *(const float4*)base;
    float s = 1.0f / deg;
    float ax = v.x * s, ay = v.y * s, az = v.z * s, aw = v.w * s;

    if (j > 0) {
        float w = dn * rsqrtf(degOf(i, j - 1));
        float4 u = *(const float4*)(base - HID);
        ax += u.x * w; ay += u.y * w; az += u.z * w; aw += u.w * w;
    }
    if (j < GRID_ - 1) {
        float w = dn * rsqrtf(degOf(i, j + 1));
        float4 u = *(const float4*)(base + HID);
        ax += u.x * w; ay += u.y * w; az += u.z * w; aw += u.w * w;
    }
    if (i > 0) {
        float w = dn * rsqrtf(degOf(i - 1, j));
        float4 u = *(const float4*)(base - GRID_ * HID);
        ax += u.x * w; ay += u.y * w; az += u.z * w; aw += u.w * w;
    }
    if (i < GRID_ - 1) {
        float w = dn * rsqrtf(degOf(i + 1, j));
        float4 u = *(const float4*)(base + GRID_ * HID);
        ax += u.x * w; ay += u.y * w; az += u.z * w; aw += u.w * w;
    }

    float4 bv = *(const float4*)(bias + d4);
    ax = fmaxf(ax + bv.x, 0.0f);
    ay = fmaxf(ay + bv.y, 0.0f);
    az = fmaxf(az + bv.z, 0.0f);
    aw = fmaxf(aw + bv.w, 0.0f);

    *(float4*)(hout + (size_t)rn * HID + d4) = make_float4(ax, ay, az, aw);
}

extern "C" void kernel_launch(void* const* d_in, const int* in_sizes, int n_in,
                              void* d_out, int out_size, void* d_ws,
                              size_t ws_size, hipStream_t stream) {
    const float* x       = (const float*)d_in[0];
    const float* W_embed = (const float*)d_in[1];
    const float* b_embed = (const float*)d_in[2];
    const float* W_gcn   = (const float*)d_in[3];
    const float* b_gcn   = (const float*)d_in[4];
    const float* W_out   = (const float*)d_in[5];
    const float* b_out   = (const float*)d_in[6];
    // d_in[7] = edge_index: static 28x28 grid, handled analytically.
    float* out = (float*)d_out;

    float* pe = (float*)d_ws;                       // 784*256 f32
    float* hA = pe + (size_t)NPATCH * HID;          // 50176*256 f32
    float* hB = hA + (size_t)MROWS * HID;           // 50176*256 f32

    pe_kernel<<<NPATCH, 256, 0, stream>>>(pe);

    // patchify + embed + bias + PE -> hA
    gemm128<true><<<dim3(MROWS / 128, 2), 256, 0, stream>>>(
        x, W_embed, b_embed, pe, hA, 192);

    for (int l = 0; l < 3; ++l) {
        gemm128<false><<<dim3(MROWS / 128, 2), 256, 0, stream>>>(
            hA, W_gcn + (size_t)l * HID * HID, nullptr, nullptr, hB, HID);
        aggregate_kernel<<<(MROWS * HID / 4) / 256, 256, 0, stream>>>(
            hB, b_gcn + (size_t)l * HID, hA);
    }

    gemm128<false><<<dim3(MROWS / 128, 2), 256, 0, stream>>>(
        hA, W_out, b_out, nullptr, out, HID);
}

// Round 7
// 261.424 us; speedup vs baseline: 2.4448x; 2.4448x over previous
//
#include <hip/hip_runtime.h>
#include <hip/hip_bf16.h>
#include <math.h>

#define GRID_ 28
#define NPATCH 784
#define HID 256
#define NB 64
#define MROWS (NB * NPATCH)   // 50176

typedef __attribute__((ext_vector_type(8))) __bf16 bf16x8;
typedef __attribute__((ext_vector_type(4))) float f32x4;

__device__ __forceinline__ float bf2f(unsigned int u16bits) {
    return __uint_as_float(u16bits << 16);
}
__device__ __forceinline__ unsigned short f2bf(float f) {
    __hip_bfloat16 h = __float2bfloat16(f);   // RNE
    return __builtin_bit_cast(unsigned short, h);
}

// ---------------- positional-encoding table: pe[784][256] f32 -------------
__global__ void pe_kernel(float* __restrict__ pe) {
    int idx = blockIdx.x * 256 + threadIdx.x;
    int n = idx >> 8;
    int d = idx & 255;
    int k = d >> 1;
    float div = expf((float)k * (-9.210340371976184f / 128.0f));
    float ang = (float)n * div;
    pe[idx] = (d & 1) ? cosf(ang) : sinf(ang);
}

// ---------------- weight transpose + f32->bf16: Wt[n][k] = W[k][n] --------
__global__ __launch_bounds__(256) void wconv(
    const float* __restrict__ We, const float* __restrict__ Wg,
    const float* __restrict__ Wo, unsigned short* __restrict__ Wte,
    unsigned short* __restrict__ Wtg, unsigned short* __restrict__ Wto) {
    int my = blockIdx.y;
    int e = blockIdx.x * 256 + threadIdx.x;
    int k = e >> 8, n = e & 255;
    if (my == 0) {
        if (k < 192) Wte[n * 192 + k] = f2bf(We[e]);
    } else if (my <= 3) {
        int l = my - 1;
        Wtg[l * 65536 + n * 256 + k] = f2bf(Wg[l * 65536 + e]);
    } else {
        Wto[n * 256 + k] = f2bf(Wo[e]);
    }
}

// ---------------- patchify: Ax[b*784+n][c*64+pi*8+pj] bf16 ---------------
__global__ void patchify(const float* __restrict__ x,
                         unsigned short* __restrict__ Ax) {
    int n = blockIdx.x, b = blockIdx.y, t = threadIdx.x;   // t in [0,192)
    int c = t >> 6, rem = t & 63, pi = rem >> 3, pj = rem & 7;
    int gi = n / GRID_, gj = n % GRID_;
    float v = x[((size_t)(b * 3 + c) * 224 + gi * 8 + pi) * 224 + gj * 8 + pj];
    Ax[(size_t)(b * NPATCH + n) * 192 + t] = f2bf(v);
}

// ---------------- MFMA GEMM: C[M,256] = A[M,K] @ Bt[256,K]^T --------------
// 128x128 tile, BK=32, 4 waves each 64x64 (4x4 frags of 16x16x32 bf16).
// EPI: 0 = bf16 out, 1 = bf16 out + bias + pe (embed), 2 = f32 out + bias.
template <int K, int EPI>
__global__ __launch_bounds__(256) void gemm_mfma(
    const unsigned short* __restrict__ A, const unsigned short* __restrict__ Bt,
    const float* __restrict__ bias, const float* __restrict__ pe,
    void* __restrict__ Cout) {
    constexpr int NT = K / 32;
    __shared__ unsigned short lds[2][2][128 * 32];   // [buf][A/B][r*32+k]

    const int tid = threadIdx.x;
    const int lane = tid & 63;
    const int wave = tid >> 6;
    const int wm = wave >> 1, wn = wave & 1;
    const int m0 = blockIdx.x * 128;
    const int n0 = blockIdx.y * 128;

    f32x4 acc[4][4];
    f32x4 zero = {0.f, 0.f, 0.f, 0.f};
#pragma unroll
    for (int i = 0; i < 4; ++i)
#pragma unroll
        for (int j = 0; j < 4; ++j) acc[i][j] = zero;

    // Staging: 512 chunks of 16B per tile; phys chunk p = it*256 + wave*64 + lane.
    // Swizzle (involution): phys (r, cp) holds logical (r, cp ^ (r&3)).
#define STAGE(BUF, KT)                                                         \
    do {                                                                       \
        const int k0s = (KT) * 32;                                             \
        _Pragma("unroll") for (int it = 0; it < 2; ++it) {                     \
            int p = it * 256 + wave * 64 + lane;                               \
            int r = p >> 2;                                                    \
            int cg = (p & 3) ^ (r & 3);                                        \
            __builtin_amdgcn_global_load_lds(                                  \
                (const __attribute__((address_space(1))) void*)(A +            \
                    (size_t)(m0 + r) * K + k0s + cg * 8),                      \
                (__attribute__((address_space(3))) void*)&lds[BUF][0]          \
                    [(it * 256 + wave * 64) * 8], 16, 0, 0);                   \
            __builtin_amdgcn_global_load_lds(                                  \
                (const __attribute__((address_space(1))) void*)(Bt +           \
                    (size_t)(n0 + r) * K + k0s + cg * 8),                      \
                (__attribute__((address_space(3))) void*)&lds[BUF][1]          \
                    [(it * 256 + wave * 64) * 8], 16, 0, 0);                   \
        }                                                                      \
    } while (0)

    STAGE(0, 0);

    for (int t = 0; t < NT; ++t) {
        __syncthreads();               // drains vmcnt (tile t ready) + lgkmcnt
        if (t + 1 < NT) STAGE((t + 1) & 1, t + 1);
        const unsigned short* As = lds[t & 1][0];
        const unsigned short* Bs = lds[t & 1][1];
        const int q = lane >> 4;
        const int rl = lane & 15;
        const int cswz = q ^ (lane & 3);       // (r&3) == (lane&3) for all frags
        bf16x8 a[4], b[4];
#pragma unroll
        for (int mi = 0; mi < 4; ++mi) {
            int ra = wm * 64 + mi * 16 + rl;
            a[mi] = *(const bf16x8*)&As[ra * 32 + cswz * 8];
        }
#pragma unroll
        for (int ni = 0; ni < 4; ++ni) {
            int rb = wn * 64 + ni * 16 + rl;
            b[ni] = *(const bf16x8*)&Bs[rb * 32 + cswz * 8];
        }
#pragma unroll
        for (int mi = 0; mi < 4; ++mi)
#pragma unroll
            for (int ni = 0; ni < 4; ++ni)
                acc[mi][ni] = __builtin_amdgcn_mfma_f32_16x16x32_bf16(
                    a[mi], b[ni], acc[mi][ni], 0, 0, 0);
    }
#undef STAGE

    // Epilogue. D layout: col = lane&15, row = (lane>>4)*4 + reg.
    const int rl = lane & 15;
    const int rq = lane >> 4;
#pragma unroll
    for (int mi = 0; mi < 4; ++mi) {
#pragma unroll
        for (int r = 0; r < 4; ++r) {
            int row = m0 + wm * 64 + mi * 16 + rq * 4 + r;
#pragma unroll
            for (int ni = 0; ni < 4; ++ni) {
                int col = n0 + wn * 64 + ni * 16 + rl;
                float v = acc[mi][ni][r];
                if constexpr (EPI == 0) {
                    ((unsigned short*)Cout)[(size_t)row * HID + col] = f2bf(v);
                } else if constexpr (EPI == 1) {
                    unsigned n = (unsigned)row % NPATCH;
                    v += bias[col] + pe[n * HID + col];
                    ((unsigned short*)Cout)[(size_t)row * HID + col] = f2bf(v);
                } else {
                    v += bias[col];
                    ((float*)Cout)[(size_t)row * HID + col] = v;
                }
            }
        }
    }
}

// ---------------- GCN aggregate (bf16 in/out): h = relu(norm-agg + b) -----
__device__ __forceinline__ float degOf(int i, int j) {
    return 1.0f + (float)((i > 0) + (i < GRID_ - 1) + (j > 0) + (j < GRID_ - 1));
}

__device__ __forceinline__ void loadf8(const unsigned short* p, float f[8],
                                       float w) {
    uint4 v = *(const uint4*)p;
    f[0] += bf2f(v.x & 0xffffu) * w;
    f[1] += bf2f(v.x >> 16) * w;
    f[2] += bf2f(v.y & 0xffffu) * w;
    f[3] += bf2f(v.y >> 16) * w;
    f[4] += bf2f(v.z & 0xffffu) * w;
    f[5] += bf2f(v.z >> 16) * w;
    f[6] += bf2f(v.w & 0xffffu) * w;
    f[7] += bf2f(v.w >> 16) * w;
}

__global__ __launch_bounds__(256) void agg(const unsigned short* __restrict__ hw,
                                           const float* __restrict__ bias,
                                           unsigned short* __restrict__ h) {
    int idx = blockIdx.x * 256 + threadIdx.x;   // MROWS*32 units of 8 bf16
    int rn = idx >> 5;
    int d8 = (idx & 31) * 8;
    unsigned n = (unsigned)rn % NPATCH;
    int i = n / GRID_, j = n % GRID_;
    float deg = degOf(i, j);
    float dn = rsqrtf(deg);

    const unsigned short* base = hw + (size_t)rn * HID + d8;
    float a[8] = {0.f, 0.f, 0.f, 0.f, 0.f, 0.f, 0.f, 0.f};
    loadf8(base, a, 1.0f / deg);
    if (j > 0)          loadf8(base - HID,         a, dn * rsqrtf(degOf(i, j - 1)));
    if (j < GRID_ - 1)  loadf8(base + HID,         a, dn * rsqrtf(degOf(i, j + 1)));
    if (i > 0)          loadf8(base - GRID_ * HID, a, dn * rsqrtf(degOf(i - 1, j)));
    if (i < GRID_ - 1)  loadf8(base + GRID_ * HID, a, dn * rsqrtf(degOf(i + 1, j)));

    float4 b0 = *(const float4*)(bias + d8);
    float4 b1 = *(const float4*)(bias + d8 + 4);
    float bv[8] = {b0.x, b0.y, b0.z, b0.w, b1.x, b1.y, b1.z, b1.w};

    unsigned r[8];
#pragma unroll
    for (int k = 0; k < 8; ++k) r[k] = f2bf(fmaxf(a[k] + bv[k], 0.0f));
    uint4 ov;
    ov.x = r[0] | (r[1] << 16);
    ov.y = r[2] | (r[3] << 16);
    ov.z = r[4] | (r[5] << 16);
    ov.w = r[6] | (r[7] << 16);
    *(uint4*)(h + (size_t)rn * HID + d8) = ov;
}

extern "C" void kernel_launch(void* const* d_in, const int* in_sizes, int n_in,
                              void* d_out, int out_size, void* d_ws,
                              size_t ws_size, hipStream_t stream) {
    const float* x       = (const float*)d_in[0];
    const float* W_embed = (const float*)d_in[1];
    const float* b_embed = (const float*)d_in[2];
    const float* W_gcn   = (const float*)d_in[3];
    const float* b_gcn   = (const float*)d_in[4];
    const float* W_out   = (const float*)d_in[5];
    const float* b_out   = (const float*)d_in[6];
    float* out = (float*)d_out;

    char* w = (char*)d_ws;
    float* pe = (float*)w;              w += (size_t)NPATCH * HID * 4;
    unsigned short* Wte = (unsigned short*)w;  w += 256 * 192 * 2;
    unsigned short* Wtg = (unsigned short*)w;  w += 3 * 256 * 256 * 2;
    unsigned short* Wto = (unsigned short*)w;  w += 256 * 256 * 2;
    unsigned short* Ax  = (unsigned short*)w;  w += (size_t)MROWS * 192 * 2;
    unsigned short* hA  = (unsigned short*)w;  w += (size_t)MROWS * HID * 2;
    unsigned short* hB  = (unsigned short*)w;  w += (size_t)MROWS * HID * 2;

    pe_kernel<<<NPATCH, 256, 0, stream>>>(pe);
    wconv<<<dim3(256, 5), 256, 0, stream>>>(W_embed, W_gcn, W_out, Wte, Wtg, Wto);
    patchify<<<dim3(NPATCH, NB), 192, 0, stream>>>(x, Ax);

    // embed: hA = Ax @ W_embed + b_embed + pe
    gemm_mfma<192, 1><<<dim3(MROWS / 128, 2), 256, 0, stream>>>(
        Ax, Wte, b_embed, pe, hA);

    for (int l = 0; l < 3; ++l) {
        gemm_mfma<256, 0><<<dim3(MROWS / 128, 2), 256, 0, stream>>>(
            hA, Wtg + (size_t)l * 65536, nullptr, nullptr, hB);
        agg<<<(MROWS * 32) / 256, 256, 0, stream>>>(hB, b_gcn + (size_t)l * HID,
                                                    hA);
    }

    gemm_mfma<256, 2><<<dim3(MROWS / 128, 2), 256, 0, stream>>>(
        hA, Wto, b_out, nullptr, out);
}

// Round 9
// 246.729 us; speedup vs baseline: 2.5904x; 1.0596x over previous
//
#include <hip/hip_runtime.h>
#include <hip/hip_bf16.h>
#include <math.h>

#define GRID_ 28
#define NPATCH 784
#define HID 256
#define NB 64
#define MROWS (NB * NPATCH)   // 50176

typedef __attribute__((ext_vector_type(8))) __bf16 bf16x8;
typedef __attribute__((ext_vector_type(4))) float f32x4;

__device__ __forceinline__ float bf2f(unsigned int u16bits) {
    return __uint_as_float(u16bits << 16);
}
__device__ __forceinline__ unsigned short f2bf(float f) {
    __hip_bfloat16 h = __float2bfloat16(f);   // RNE
    return __builtin_bit_cast(unsigned short, h);
}

// ---------------- positional-encoding table: pe[784][256] f32 -------------
__global__ void pe_kernel(float* __restrict__ pe) {
    int idx = blockIdx.x * 256 + threadIdx.x;
    int n = idx >> 8;
    int d = idx & 255;
    int k = d >> 1;
    float div = expf((float)k * (-9.210340371976184f / 128.0f));
    float ang = (float)n * div;
    pe[idx] = (d & 1) ? cosf(ang) : sinf(ang);
}

// ------- weight transpose + cast via LDS 64x64 tile: Wt[n][k] = W[k][n] ---
__global__ __launch_bounds__(256) void wconv_t(
    const float* __restrict__ We, const float* __restrict__ Wg,
    const float* __restrict__ Wo, unsigned short* __restrict__ Wte,
    unsigned short* __restrict__ Wtg, unsigned short* __restrict__ Wto) {
    __shared__ float t[64][65];
    int m = blockIdx.y;                      // 0:We, 1..3:Wg[l], 4:Wo
    const float* src;
    unsigned short* dst;
    int K;
    if (m == 0)      { src = We;                  dst = Wte;                  K = 192; }
    else if (m <= 3) { src = Wg + (m - 1) * 65536; dst = Wtg + (m - 1) * 65536; K = 256; }
    else             { src = Wo;                  dst = Wto;                  K = 256; }
    const int ntk = K >> 6;                  // tiles along k
    int tile = blockIdx.x;
    if (tile >= ntk * 4) return;             // N=256 -> 4 n-tiles
    int kt = tile >> 2, nt = tile & 3;
    int k0 = kt * 64, n0 = nt * 64;
    int tc = threadIdx.x & 63, tr = threadIdx.x >> 6;
#pragma unroll
    for (int p = 0; p < 16; ++p) {
        int r = p * 4 + tr;
        t[r][tc] = src[(size_t)(k0 + r) * 256 + n0 + tc];
    }
    __syncthreads();
#pragma unroll
    for (int p = 0; p < 2; ++p) {
        int ch = p * 256 + threadIdx.x;
        int rr = ch >> 3, cc = ch & 7;       // dst row (n), 8-k chunk
        unsigned short o[8];
#pragma unroll
        for (int e = 0; e < 8; ++e) o[e] = f2bf(t[cc * 8 + e][rr]);
        *(uint4*)(dst + (size_t)(n0 + rr) * K + k0 + cc * 8) = *(uint4*)o;
    }
}

// ------- patchify: one thread = one 8-px patch row (16B bf16 store) -------
__global__ __launch_bounds__(256) void patchify8(const float* __restrict__ x,
                                                 unsigned short* __restrict__ Ax) {
    int g = blockIdx.x * 256 + threadIdx.x;   // chunk id, total MROWS*24
    int rn = g / 24;                          // b*784+n
    int fc = g - rn * 24;                     // c*8 + pi
    int c = fc >> 3, pi = fc & 7;
    int b = rn / NPATCH, n = rn - b * NPATCH;
    int gi = n / GRID_, gj = n - gi * GRID_;
    const float* src =
        x + ((size_t)(b * 3 + c) * 224 + gi * 8 + pi) * 224 + gj * 8;
    float4 v0 = *(const float4*)src;
    float4 v1 = *(const float4*)(src + 4);
    unsigned short o[8] = {f2bf(v0.x), f2bf(v0.y), f2bf(v0.z), f2bf(v0.w),
                           f2bf(v1.x), f2bf(v1.y), f2bf(v1.z), f2bf(v1.w)};
    *(uint4*)(Ax + (size_t)rn * 192 + fc * 8) = *(uint4*)o;
}

// ---------------- MFMA GEMM: C[M,256] = A[M,K] @ Bt[256,K]^T --------------
// 128x128 tile, BK=32, 4 waves each 64x64 (4x4 frags of 16x16x32 bf16).
// EPI: 0 = bf16 out, 1 = bf16 out + bias + pe (embed), 2 = f32 out + bias.
template <int K, int EPI>
__global__ __launch_bounds__(256) void gemm_mfma(
    const unsigned short* __restrict__ A, const unsigned short* __restrict__ Bt,
    const float* __restrict__ bias, const float* __restrict__ pe,
    void* __restrict__ Cout) {
    constexpr int NT = K / 32;
    __shared__ unsigned short lds[2][2][128 * 32];   // [buf][A/B][r*32+k]

    const int tid = threadIdx.x;
    const int lane = tid & 63;
    const int wave = tid >> 6;
    const int wm = wave >> 1, wn = wave & 1;
    const int m0 = blockIdx.x * 128;
    const int n0 = blockIdx.y * 128;

    f32x4 acc[4][4];
    f32x4 zero = {0.f, 0.f, 0.f, 0.f};
#pragma unroll
    for (int i = 0; i < 4; ++i)
#pragma unroll
        for (int j = 0; j < 4; ++j) acc[i][j] = zero;

    // Staging: 512 chunks of 16B per tile; phys chunk p = it*256 + wave*64 + lane.
    // Swizzle (involution): phys (r, cp) holds logical (r, cp ^ (r&3)).
#define STAGE(BUF, KT)                                                         \
    do {                                                                       \
        const int k0s = (KT) * 32;                                             \
        _Pragma("unroll") for (int it = 0; it < 2; ++it) {                     \
            int p = it * 256 + wave * 64 + lane;                               \
            int r = p >> 2;                                                    \
            int cg = (p & 3) ^ (r & 3);                                        \
            __builtin_amdgcn_global_load_lds(                                  \
                (const __attribute__((address_space(1))) void*)(A +            \
                    (size_t)(m0 + r) * K + k0s + cg * 8),                      \
                (__attribute__((address_space(3))) void*)&lds[BUF][0]          \
                    [(it * 256 + wave * 64) * 8], 16, 0, 0);                   \
            __builtin_amdgcn_global_load_lds(                                  \
                (const __attribute__((address_space(1))) void*)(Bt +           \
                    (size_t)(n0 + r) * K + k0s + cg * 8),                      \
                (__attribute__((address_space(3))) void*)&lds[BUF][1]          \
                    [(it * 256 + wave * 64) * 8], 16, 0, 0);                   \
        }                                                                      \
    } while (0)

    STAGE(0, 0);

#pragma unroll
    for (int t = 0; t < NT; ++t) {
        __syncthreads();               // drains vmcnt (tile t ready) + lgkmcnt
        if (t + 1 < NT) STAGE((t + 1) & 1, t + 1);
        const unsigned short* As = lds[t & 1][0];
        const unsigned short* Bs = lds[t & 1][1];
        const int q = lane >> 4;
        const int rl = lane & 15;
        const int cswz = q ^ (lane & 3);       // (r&3) == (lane&3) for all frags
        bf16x8 a[4], b[4];
#pragma unroll
        for (int mi = 0; mi < 4; ++mi) {
            int ra = wm * 64 + mi * 16 + rl;
            a[mi] = *(const bf16x8*)&As[ra * 32 + cswz * 8];
        }
#pragma unroll
        for (int ni = 0; ni < 4; ++ni) {
            int rb = wn * 64 + ni * 16 + rl;
            b[ni] = *(const bf16x8*)&Bs[rb * 32 + cswz * 8];
        }
#pragma unroll
        for (int mi = 0; mi < 4; ++mi)
#pragma unroll
            for (int ni = 0; ni < 4; ++ni)
                acc[mi][ni] = __builtin_amdgcn_mfma_f32_16x16x32_bf16(
                    a[mi], b[ni], acc[mi][ni], 0, 0, 0);
    }
#undef STAGE

    // Epilogue. D layout: col = lane&15, row = (lane>>4)*4 + reg.
    const int rl = lane & 15;
    const int rq = lane >> 4;
#pragma unroll
    for (int mi = 0; mi < 4; ++mi) {
#pragma unroll
        for (int r = 0; r < 4; ++r) {
            int row = m0 + wm * 64 + mi * 16 + rq * 4 + r;
#pragma unroll
            for (int ni = 0; ni < 4; ++ni) {
                int col = n0 + wn * 64 + ni * 16 + rl;
                float v = acc[mi][ni][r];
                if constexpr (EPI == 0) {
                    ((unsigned short*)Cout)[(size_t)row * HID + col] = f2bf(v);
                } else if constexpr (EPI == 1) {
                    unsigned n = (unsigned)row % NPATCH;
                    v += bias[col] + pe[n * HID + col];
                    ((unsigned short*)Cout)[(size_t)row * HID + col] = f2bf(v);
                } else {
                    v += bias[col];
                    ((float*)Cout)[(size_t)row * HID + col] = v;
                }
            }
        }
    }
}

// ---------------- GCN aggregate (bf16 in/out): h = relu(norm-agg + b) -----
__device__ __forceinline__ float degOf(int i, int j) {
    return 1.0f + (float)((i > 0) + (i < GRID_ - 1) + (j > 0) + (j < GRID_ - 1));
}

__device__ __forceinline__ void loadf8(const unsigned short* p, float f[8],
                                       float w) {
    uint4 v = *(const uint4*)p;
    f[0] += bf2f(v.x & 0xffffu) * w;
    f[1] += bf2f(v.x >> 16) * w;
    f[2] += bf2f(v.y & 0xffffu) * w;
    f[3] += bf2f(v.y >> 16) * w;
    f[4] += bf2f(v.z & 0xffffu) * w;
    f[5] += bf2f(v.z >> 16) * w;
    f[6] += bf2f(v.w & 0xffffu) * w;
    f[7] += bf2f(v.w >> 16) * w;
}

__global__ __launch_bounds__(256) void agg(const unsigned short* __restrict__ hw,
                                           const float* __restrict__ bias,
                                           unsigned short* __restrict__ h) {
    int idx = blockIdx.x * 256 + threadIdx.x;   // MROWS*32 units of 8 bf16
    int rn = idx >> 5;
    int d8 = (idx & 31) * 8;
    unsigned n = (unsigned)rn % NPATCH;
    int i = n / GRID_, j = n % GRID_;
    float deg = degOf(i, j);
    float dn = rsqrtf(deg);

    const unsigned short* base = hw + (size_t)rn * HID + d8;
    float a[8] = {0.f, 0.f, 0.f, 0.f, 0.f, 0.f, 0.f, 0.f};
    loadf8(base, a, 1.0f / deg);
    if (j > 0)          loadf8(base - HID,         a, dn * rsqrtf(degOf(i, j - 1)));
    if (j < GRID_ - 1)  loadf8(base + HID,         a, dn * rsqrtf(degOf(i, j + 1)));
    if (i > 0)          loadf8(base - GRID_ * HID, a, dn * rsqrtf(degOf(i - 1, j)));
    if (i < GRID_ - 1)  loadf8(base + GRID_ * HID, a, dn * rsqrtf(degOf(i + 1, j)));

    float4 b0 = *(const float4*)(bias + d8);
    float4 b1 = *(const float4*)(bias + d8 + 4);
    float bv[8] = {b0.x, b0.y, b0.z, b0.w, b1.x, b1.y, b1.z, b1.w};

    unsigned r[8];
#pragma unroll
    for (int k = 0; k < 8; ++k) r[k] = f2bf(fmaxf(a[k] + bv[k], 0.0f));
    uint4 ov;
    ov.x = r[0] | (r[1] << 16);
    ov.y = r[2] | (r[3] << 16);
    ov.z = r[4] | (r[5] << 16);
    ov.w = r[6] | (r[7] << 16);
    *(uint4*)(h + (size_t)rn * HID + d8) = ov;
}

extern "C" void kernel_launch(void* const* d_in, const int* in_sizes, int n_in,
                              void* d_out, int out_size, void* d_ws,
                              size_t ws_size, hipStream_t stream) {
    const float* x       = (const float*)d_in[0];
    const float* W_embed = (const float*)d_in[1];
    const float* b_embed = (const float*)d_in[2];
    const float* W_gcn   = (const float*)d_in[3];
    const float* b_gcn   = (const float*)d_in[4];
    const float* W_out   = (const float*)d_in[5];
    const float* b_out   = (const float*)d_in[6];
    float* out = (float*)d_out;

    char* w = (char*)d_ws;
    float* pe = (float*)w;              w += (size_t)NPATCH * HID * 4;
    unsigned short* Wte = (unsigned short*)w;  w += 256 * 192 * 2;
    unsigned short* Wtg = (unsigned short*)w;  w += 3 * 256 * 256 * 2;
    unsigned short* Wto = (unsigned short*)w;  w += 256 * 256 * 2;
    unsigned short* Ax  = (unsigned short*)w;  w += (size_t)MROWS * 192 * 2;
    unsigned short* hA  = (unsigned short*)w;  w += (size_t)MROWS * HID * 2;
    unsigned short* hB  = (unsigned short*)w;  w += (size_t)MROWS * HID * 2;

    pe_kernel<<<NPATCH, 256, 0, stream>>>(pe);
    wconv_t<<<dim3(16, 5), 256, 0, stream>>>(W_embed, W_gcn, W_out, Wte, Wtg,
                                             Wto);
    patchify8<<<(MROWS * 24) / 256, 256, 0, stream>>>(x, Ax);

    // embed: hA = Ax @ W_embed + b_embed + pe
    gemm_mfma<192, 1><<<dim3(MROWS / 128, 2), 256, 0, stream>>>(
        Ax, Wte, b_embed, pe, hA);

    for (int l = 0; l < 3; ++l) {
        gemm_mfma<256, 0><<<dim3(MROWS / 128, 2), 256, 0, stream>>>(
            hA, Wtg + (size_t)l * 65536, nullptr, nullptr, hB);
        agg<<<(MROWS * 32) / 256, 256, 0, stream>>>(hB, b_gcn + (size_t)l * HID,
                                                    hA);
    }

    gemm_mfma<256, 2><<<dim3(MROWS / 128, 2), 256, 0, stream>>>(
        hA, Wto, b_out, nullptr, out);
}